// Round 1
// baseline (508.744 us; speedup 1.0000x reference)
//
#include <hip/hip_runtime.h>

typedef _Float16 f16;
typedef _Float16 f16x8 __attribute__((ext_vector_type(8)));
typedef _Float16 f16x4 __attribute__((ext_vector_type(4)));
typedef float f32x4 __attribute__((ext_vector_type(4)));

#define B_    2048
#define I_    1024
#define H_    2048
#define C_    1000
#define S_    8
#define N1    32768   /* S * 2H */
#define TOPK_ 256

// ---------------- global -> LDS async stage (16B per lane) ----------------
__device__ __forceinline__ void gload16(const void* g, void* l) {
  __builtin_amdgcn_global_load_lds((const __attribute__((address_space(1))) void*)g,
                                   (__attribute__((address_space(3))) void*)l,
                                   16, 0, 0);
}

// ---------------- f32 -> f16 converts ----------------
__global__ void cvt_f16_kernel(const float* __restrict__ src, f16* __restrict__ dst, int n4) {
  int i = blockIdx.x * blockDim.x + threadIdx.x;
  if (i >= n4) return;
  const float4 v = reinterpret_cast<const float4*>(src)[i];
  f16x4 o = { (f16)v.x, (f16)v.y, (f16)v.z, (f16)v.w };
  reinterpret_cast<f16x4*>(dst)[i] = o;
}

// clf_W (1000x2048) -> padded (1024x2048) f16, pad rows zero
__global__ void cvt_clf_kernel(const float* __restrict__ src, f16* __restrict__ dst) {
  int i = blockIdx.x * blockDim.x + threadIdx.x;   // over 1024*2048/4 chunks
  if (i >= (1024 * H_ / 4)) return;
  f16x4 o;
  if (i < (C_ * H_ / 4)) {
    const float4 v = reinterpret_cast<const float4*>(src)[i];
    o = (f16x4){ (f16)v.x, (f16)v.y, (f16)v.z, (f16)v.w };
  } else {
    o = (f16x4){ (f16)0.f, (f16)0.f, (f16)0.f, (f16)0.f };
  }
  reinterpret_cast<f16x4*>(dst)[i] = o;
}

__global__ void phase_kernel(const float* __restrict__ ph, float* __restrict__ c,
                             float* __restrict__ s) {
  int i = blockIdx.x * blockDim.x + threadIdx.x;
  if (i >= S_ * H_) return;
  float p = ph[i];
  c[i] = cosf(p);
  s[i] = sinf(p);
}

// ---------------- GEMM C[m,n] = sum_k A[m,k]*B[n,k]  (B^T layout) ----------------
// 128x128 tile, BK=32, 256 threads (4 waves 2x2), 16x16x32 f16 MFMA, 4x4 frags/wave.
// EPI 0: act = exp(-(t)^2) -> f16     (t = acc + bias[col])
// EPI 1: g = sigmoid(t); sup_r/i *= g in place; write mag f16 (or mag_sq f32 if mag_out==null)
// EPI 2: logits = t -> f32 (col < nreal)
template<int EPI>
__global__ __launch_bounds__(256)
void gemm_bt(const f16* __restrict__ A, const f16* __restrict__ Bm,
             const int K, const int NT, const int ldc, const int nreal,
             const float* __restrict__ bias,
             f16* __restrict__ act_out,
             float* __restrict__ supr, float* __restrict__ supi,
             f16* __restrict__ mag_out, float* __restrict__ magsq_out,
             float* __restrict__ logits)
{
  __shared__ f16 As[128 * 32];
  __shared__ f16 Bs[128 * 32];
  const int tid  = threadIdx.x;
  const int lane = tid & 63, wave = tid >> 6;
  const int mt = blockIdx.x / NT, nt = blockIdx.x % NT;
  const long brow = (long)mt * 128, bcol = (long)nt * 128;
  const int wr = wave >> 1, wc = wave & 1;
  const int fr = lane & 15, fq = lane >> 4;
  const int r_in = lane >> 2;          // row within 16-row chunk (4 lanes per 64B row)
  const int k8   = (lane & 3) * 8;     // k element offset within row

  f32x4 acc[4][4] = {};

  // staging bases: wave stages 2 chunks of 16 rows each for A and B
  const f16* Ab = A  + (brow + wave * 32 + r_in) * (long)K + k8;
  const f16* Bb = Bm + (bcol + wave * 32 + r_in) * (long)K + k8;
  f16* Asw = &As[wave * 1024];   // 2 chunks * 512 f16
  f16* Bsw = &Bs[wave * 1024];

  for (int kt = 0; kt < K; kt += 32) {
    gload16(Ab + kt,                 Asw);
    gload16(Ab + kt + (long)16 * K,  Asw + 512);
    gload16(Bb + kt,                 Bsw);
    gload16(Bb + kt + (long)16 * K,  Bsw + 512);
    __syncthreads();   // drains vmcnt before barrier -> LDS ready

    f16x8 af[4], bf[4];
#pragma unroll
    for (int m = 0; m < 4; ++m)
      af[m] = *(const f16x8*)&As[(wr * 64 + m * 16 + fr) * 32 + fq * 8];
#pragma unroll
    for (int n = 0; n < 4; ++n)
      bf[n] = *(const f16x8*)&Bs[(wc * 64 + n * 16 + fr) * 32 + fq * 8];
#pragma unroll
    for (int m = 0; m < 4; ++m)
#pragma unroll
      for (int n = 0; n < 4; ++n)
        acc[m][n] = __builtin_amdgcn_mfma_f32_16x16x32_f16(af[m], bf[n], acc[m][n], 0, 0, 0);
    __syncthreads();   // protect LDS before next stage
  }

#pragma unroll
  for (int m = 0; m < 4; ++m) {
    const long r0 = brow + wr * 64 + m * 16 + fq * 4;
#pragma unroll
    for (int n = 0; n < 4; ++n) {
      const long c = bcol + wc * 64 + n * 16 + fr;
      float bv;
      if (EPI == 2) bv = (c < nreal) ? bias[c] : 0.f;
      else          bv = bias[c];
#pragma unroll
      for (int j = 0; j < 4; ++j) {
        const long r = r0 + j;
        const float t = acc[m][n][j] + bv;
        if (EPI == 0) {
          act_out[r * (long)ldc + c] = (f16)expf(-t * t);
        } else if (EPI == 1) {
          const float g = 1.f / (1.f + expf(-t));
          const long idx = r * (long)ldc + c;
          const float srv = supr[idx] * g;
          const float siv = supi[idx] * g;
          supr[idx] = srv;
          supi[idx] = siv;
          if (mag_out) mag_out[idx] = (f16)sqrtf(srv * srv + siv * siv);
          else         magsq_out[idx] = srv * srv + siv * siv;
        } else {
          if (c < nreal) logits[r * (long)nreal + c] = t;
        }
      }
    }
  }
}

// ---------------- per-row norm + supposition ----------------
// block = one b row (512 threads); for each s: load act[b,s,0:4096] f16, sum of squares,
// factor = 1/sqrt(sum+EPS), accumulate sup_real/imag with cos/sin tables.
__global__ __launch_bounds__(512)
void normsup_kernel(const f16* __restrict__ act,
                    const float* __restrict__ cphi, const float* __restrict__ sphi,
                    float* __restrict__ supr, float* __restrict__ supi,
                    f16* __restrict__ mag0)
{
  __shared__ float buf[4096];
  __shared__ float red[8];
  const int b = blockIdx.x, tid = threadIdx.x;
  const int lane = tid & 63, wv = tid >> 6;
  float sr[4] = {0, 0, 0, 0}, si[4] = {0, 0, 0, 0};
  const f16* base = act + (size_t)b * N1;

  for (int s = 0; s < S_; ++s) {
    f16x8 v = *(const f16x8*)(base + s * 4096 + tid * 8);
    float ls = 0.f;
#pragma unroll
    for (int e = 0; e < 8; ++e) {
      float f = (float)v[e];
      buf[tid * 8 + e] = f;
      ls += f * f;
    }
#pragma unroll
    for (int o = 32; o > 0; o >>= 1) ls += __shfl_down(ls, o);
    if (lane == 0) red[wv] = ls;
    __syncthreads();
    const float tot = red[0] + red[1] + red[2] + red[3] + red[4] + red[5] + red[6] + red[7];
    const float factor = 1.f / sqrtf(tot + 1e-8f);

    const float4 c4 = *(const float4*)(cphi + s * H_ + tid * 4);
    const float4 s4 = *(const float4*)(sphi + s * H_ + tid * 4);
    const float4 a4 = *(const float4*)(&buf[tid * 4]);
    const float4 b4 = *(const float4*)(&buf[2048 + tid * 4]);
    sr[0] += factor * (a4.x * c4.x - b4.x * s4.x); si[0] += factor * (a4.x * s4.x + b4.x * c4.x);
    sr[1] += factor * (a4.y * c4.y - b4.y * s4.y); si[1] += factor * (a4.y * s4.y + b4.y * c4.y);
    sr[2] += factor * (a4.z * c4.z - b4.z * s4.z); si[2] += factor * (a4.z * s4.z + b4.z * c4.z);
    sr[3] += factor * (a4.w * c4.w - b4.w * s4.w); si[3] += factor * (a4.w * s4.w + b4.w * c4.w);
    __syncthreads();   // buf reused next s
  }

  const size_t o = (size_t)b * H_ + tid * 4;
  *(float4*)(supr + o) = make_float4(sr[0], sr[1], sr[2], sr[3]);
  *(float4*)(supi + o) = make_float4(si[0], si[1], si[2], si[3]);
  f16x4 m = { (f16)sqrtf(sr[0] * sr[0] + si[0] * si[0]),
              (f16)sqrtf(sr[1] * sr[1] + si[1] * si[1]),
              (f16)sqrtf(sr[2] * sr[2] + si[2] * si[2]),
              (f16)sqrtf(sr[3] * sr[3] + si[3] * si[3]) };
  *(f16x4*)(mag0 + o) = m;
}

// ---------------- top-k (256 of 2048) + prob normalize ----------------
// Radix select on f32 bit patterns (all values >= 0 so uint order == float order).
// Ties at threshold resolved by smallest index (matches jax.lax.top_k).
__global__ __launch_bounds__(256)
void topk_kernel(const float* __restrict__ msq, f16* __restrict__ probs)
{
  __shared__ unsigned vals[2048];
  __shared__ int hist[256];
  __shared__ int scn[256];
  __shared__ int sdig, sknew;
  __shared__ float wsum[4];
  const int b = blockIdx.x, tid = threadIdx.x;
  const unsigned* row = (const unsigned*)(msq + (size_t)b * H_);

  uint4 v0 = *(const uint4*)(row + tid * 8);
  uint4 v1 = *(const uint4*)(row + tid * 8 + 4);
  vals[tid * 8 + 0] = v0.x; vals[tid * 8 + 1] = v0.y;
  vals[tid * 8 + 2] = v0.z; vals[tid * 8 + 3] = v0.w;
  vals[tid * 8 + 4] = v1.x; vals[tid * 8 + 5] = v1.y;
  vals[tid * 8 + 6] = v1.z; vals[tid * 8 + 7] = v1.w;
  __syncthreads();

  int k = TOPK_;
  unsigned prefix = 0, pmask = 0;
  for (int pass = 0; pass < 4; ++pass) {
    const int sh = 24 - pass * 8;
    hist[tid] = 0;
    __syncthreads();
#pragma unroll
    for (int e = 0; e < 8; ++e) {
      unsigned v = vals[tid * 8 + e];
      if ((v & pmask) == prefix) atomicAdd(&hist[(v >> sh) & 255u], 1);
    }
    __syncthreads();
    const int own = hist[tid];
    int sc = own;
    scn[tid] = sc;
    __syncthreads();
    for (int o2 = 1; o2 < 256; o2 <<= 1) {   // suffix sums: scn[d] = sum_{d'>=d} hist[d']
      int add = (tid + o2 < 256) ? scn[tid + o2] : 0;
      __syncthreads();
      sc += add; scn[tid] = sc;
      __syncthreads();
    }
    if (sc >= k && (sc - own) < k) { sdig = tid; sknew = k - (sc - own); }
    __syncthreads();
    prefix |= ((unsigned)sdig) << sh;
    pmask  |= 0xFFu << sh;
    k = sknew;
    __syncthreads();
  }

  const unsigned T = prefix;
  const int krem = k;                    // # of ==T elements to include (by index)
  unsigned vl[8];
  int eqc = 0;
#pragma unroll
  for (int e = 0; e < 8; ++e) { vl[e] = vals[tid * 8 + e]; if (vl[e] == T) eqc++; }
  int sc2 = eqc;
  scn[tid] = sc2;
  __syncthreads();
  for (int o2 = 1; o2 < 256; o2 <<= 1) {  // inclusive prefix over thread chunks (index order)
    int add = (tid >= o2) ? scn[tid - o2] : 0;
    __syncthreads();
    sc2 += add; scn[tid] = sc2;
    __syncthreads();
  }
  int rank = sc2 - eqc;                  // exclusive prefix of equal-count
  float ls = 0.f;
  bool sel[8];
#pragma unroll
  for (int e = 0; e < 8; ++e) {
    const unsigned v = vl[e];
    bool s_ = false;
    if (v > T) s_ = true;
    else if (v == T) { s_ = (rank < krem); ++rank; }
    sel[e] = s_;
    if (s_) ls += __uint_as_float(v);
  }
#pragma unroll
  for (int o2 = 32; o2 > 0; o2 >>= 1) ls += __shfl_down(ls, o2);
  if ((tid & 63) == 0) wsum[tid >> 6] = ls;
  __syncthreads();
  const float tot = wsum[0] + wsum[1] + wsum[2] + wsum[3];
  const float inv = 1.f / (tot + 1e-8f);
  f16x8 ov;
#pragma unroll
  for (int e = 0; e < 8; ++e)
    ov[e] = sel[e] ? (f16)(__uint_as_float(vl[e]) * inv) : (f16)0.f;
  *(f16x8*)(probs + (size_t)b * H_ + tid * 8) = ov;
}

// ---------------- launch ----------------
extern "C" void kernel_launch(void* const* d_in, const int* in_sizes, int n_in,
                              void* d_out, int out_size, void* d_ws, size_t ws_size,
                              hipStream_t stream)
{
  const float* x  = (const float*)d_in[0];
  const float* W  = (const float*)d_in[1];
  const float* bb = (const float*)d_in[2];
  const float* ph = (const float*)d_in[3];
  const float* gW = (const float*)d_in[4];
  const float* gb = (const float*)d_in[5];
  const float* cW = (const float*)d_in[6];
  const float* cb = (const float*)d_in[7];
  float* out = (float*)d_out;

  char* base = (char*)d_ws;
  size_t off = 0;
  auto take = [&](size_t bytes) -> char* {
    char* r = base + off;
    off += (bytes + 255) & ~(size_t)255;
    return r;
  };
  f16*   Wf   = (f16*)  take((size_t)S_ * 2 * H_ * I_ * 2);   //  67.1 MB
  f16*   xf   = (f16*)  take((size_t)B_ * I_ * 2);            //   4.2 MB
  f16*   gWf  = (f16*)  take((size_t)H_ * H_ * 2);            //   8.4 MB
  f16*   cWf  = (f16*)  take((size_t)1024 * H_ * 2);          //   4.2 MB (padded)
  float* cphi = (float*)take((size_t)S_ * H_ * 4);
  float* sphi = (float*)take((size_t)S_ * H_ * 4);
  f16*   act  = (f16*)  take((size_t)B_ * N1 * 2);            // 134.2 MB
  float* supr = (float*)take((size_t)B_ * H_ * 4);            //  16.8 MB
  float* supi = (float*)take((size_t)B_ * H_ * 4);            //  16.8 MB
  f16*   mag0 = (f16*)  take((size_t)B_ * H_ * 2);            //   8.4 MB
  f16*   mag1 = (f16*)  take((size_t)B_ * H_ * 2);            //   8.4 MB
  float* msq  = (float*)take((size_t)B_ * H_ * 4);            //  16.8 MB
  f16*   probs= (f16*)  take((size_t)B_ * H_ * 2);            //   8.4 MB
  (void)ws_size; (void)in_sizes; (void)n_in; (void)out_size;  // total ~294 MB

  // converts + tables
  cvt_f16_kernel<<<(S_ * 2 * H_ * I_ / 4 + 255) / 256, 256, 0, stream>>>(W, Wf, S_ * 2 * H_ * I_ / 4);
  cvt_f16_kernel<<<(B_ * I_ / 4 + 255) / 256, 256, 0, stream>>>(x, xf, B_ * I_ / 4);
  cvt_f16_kernel<<<(H_ * H_ / 4 + 255) / 256, 256, 0, stream>>>(gW, gWf, H_ * H_ / 4);
  cvt_clf_kernel<<<(1024 * H_ / 4 + 255) / 256, 256, 0, stream>>>(cW, cWf);
  phase_kernel<<<(S_ * H_ + 255) / 256, 256, 0, stream>>>(ph, cphi, sphi);

  // 1) out = x @ W^T + b ; act = exp(-out^2)
  gemm_bt<0><<<(B_ / 128) * (N1 / 128), 256, 0, stream>>>(
      xf, Wf, I_, N1 / 128, N1, N1, bb, act,
      nullptr, nullptr, nullptr, nullptr, nullptr);

  // 2) normalize + supposition -> sup_r, sup_i, mag0
  normsup_kernel<<<B_, 512, 0, stream>>>(act, cphi, sphi, supr, supi, mag0);

  // 3) gate step 1: g = sigmoid(mag0 @ gW^T + gb); sup *= g; mag1
  gemm_bt<1><<<(B_ / 128) * (H_ / 128), 256, 0, stream>>>(
      mag0, gWf, H_, H_ / 128, H_, H_, gb, nullptr,
      supr, supi, mag1, nullptr, nullptr);

  // 4) gate step 2: same from mag1; write mag_sq
  gemm_bt<1><<<(B_ / 128) * (H_ / 128), 256, 0, stream>>>(
      mag1, gWf, H_, H_ / 128, H_, H_, gb, nullptr,
      supr, supi, nullptr, msq, nullptr);

  // 5) top-256 + prob normalize
  topk_kernel<<<B_, 256, 0, stream>>>(msq, probs);

  // 6) logits = probs @ clf_W^T + clf_b
  gemm_bt<2><<<(B_ / 128) * (1024 / 128), 256, 0, stream>>>(
      probs, cWf, H_, 1024 / 128, 0, C_, cb, nullptr,
      nullptr, nullptr, nullptr, nullptr, out);
}